// Round 1
// baseline (491.188 us; speedup 1.0000x reference)
//
#include <hip/hip_runtime.h>
#include <hip/hip_bf16.h>
#include <math.h>

// Problem constants (fixed by setup_inputs): N=2048, D=512, K=65536
#define N_ROWS 2048
#define D_DIM  512
#define K_NEG  65536
#define INV_T  5.0f   // 1/0.2

typedef __bf16 bf16x8 __attribute__((ext_vector_type(8)));
typedef float  f32x4  __attribute__((ext_vector_type(4)));

__device__ __forceinline__ void gload_lds16(const __bf16* g, __bf16* l) {
    __builtin_amdgcn_global_load_lds(
        (const __attribute__((address_space(1))) void*)g,
        (__attribute__((address_space(3))) void*)l, 16, 0, 0);
}

// ---------------------------------------------------------------------------
// Kernel 1 (merged preps): one wave per row, 4 rows/block.  (unchanged)
//  blocks [0, 512):          query/keys -> Abf, sq=5/||q||, lpos, rowsum=exp(lpos)
//  blocks [512, 512+16384):  queue -> Bbf, ru=1/||u||
// ---------------------------------------------------------------------------
__global__ __launch_bounds__(256) void prep_all_kernel(
    const float* __restrict__ query, const float* __restrict__ keys,
    const float* __restrict__ queue,
    __bf16* __restrict__ Abf, __bf16* __restrict__ Bbf,
    float* __restrict__ sq, float* __restrict__ ru,
    float* __restrict__ lpos, float* __restrict__ rowsum) {
    const int lane = threadIdx.x & 63;
    if (blockIdx.x < N_ROWS / 4) {
        const int row = blockIdx.x * 4 + (threadIdx.x >> 6);
        const float4* qv = reinterpret_cast<const float4*>(query + (size_t)row * D_DIM) + lane * 2;
        const float4* kv = reinterpret_cast<const float4*>(keys  + (size_t)row * D_DIM) + lane * 2;
        float4 q0 = qv[0], q1 = qv[1];
        float4 k0 = kv[0], k1 = kv[1];
        float ssq = q0.x*q0.x + q0.y*q0.y + q0.z*q0.z + q0.w*q0.w
                  + q1.x*q1.x + q1.y*q1.y + q1.z*q1.z + q1.w*q1.w;
        float ssk = k0.x*k0.x + k0.y*k0.y + k0.z*k0.z + k0.w*k0.w
                  + k1.x*k1.x + k1.y*k1.y + k1.z*k1.z + k1.w*k1.w;
        float dot = q0.x*k0.x + q0.y*k0.y + q0.z*k0.z + q0.w*k0.w
                  + q1.x*k1.x + q1.y*k1.y + q1.z*k1.z + q1.w*k1.w;
#pragma unroll
        for (int off = 32; off > 0; off >>= 1) {
            ssq += __shfl_xor(ssq, off, 64);
            ssk += __shfl_xor(ssk, off, 64);
            dot += __shfl_xor(dot, off, 64);
        }
        bf16x8 o;
        o[0] = (__bf16)q0.x; o[1] = (__bf16)q0.y; o[2] = (__bf16)q0.z; o[3] = (__bf16)q0.w;
        o[4] = (__bf16)q1.x; o[5] = (__bf16)q1.y; o[6] = (__bf16)q1.z; o[7] = (__bf16)q1.w;
        reinterpret_cast<bf16x8*>(Abf + (size_t)row * D_DIM)[lane] = o;
        if (lane == 0) {
            float qn = sqrtf(ssq), kn = sqrtf(ssk);
            float lp = dot / fmaxf(qn * kn, 1e-8f) * INV_T;
            sq[row]     = INV_T / fmaxf(qn, 1e-8f);
            lpos[row]   = lp;
            rowsum[row] = __expf(lp);   // positive-logit term; also inits accumulator
        }
    } else {
        const int row = (blockIdx.x - N_ROWS / 4) * 4 + (threadIdx.x >> 6);
        const float4* uv = reinterpret_cast<const float4*>(queue + (size_t)row * D_DIM) + lane * 2;
        float4 u0 = uv[0], u1 = uv[1];
        float ss = u0.x*u0.x + u0.y*u0.y + u0.z*u0.z + u0.w*u0.w
                 + u1.x*u1.x + u1.y*u1.y + u1.z*u1.z + u1.w*u1.w;
#pragma unroll
        for (int off = 32; off > 0; off >>= 1) ss += __shfl_xor(ss, off, 64);
        bf16x8 o;
        o[0] = (__bf16)u0.x; o[1] = (__bf16)u0.y; o[2] = (__bf16)u0.z; o[3] = (__bf16)u0.w;
        o[4] = (__bf16)u1.x; o[5] = (__bf16)u1.y; o[6] = (__bf16)u1.z; o[7] = (__bf16)u1.w;
        reinterpret_cast<bf16x8*>(Bbf + (size_t)row * D_DIM)[lane] = o;
        if (lane == 0) ru[row] = 1.0f / fmaxf(sqrtf(ss), 1e-8f);
    }
}

// ---------------------------------------------------------------------------
// Kernel 2: NT-GEMM with fused exp-rowsum — 256x256 8-phase template (T2+T3+T4+T5).
// 512 threads = 8 waves (2M x 4N); wave tile 128x64; BK=64; K=512 -> 8 K-tiles.
// LDS 128 KiB: sA/sB each 2 slots x [256][64] bf16, slot = K-tile parity.
// Per iteration (2 K-tiles, 8 phases): each phase = {ds_read frag subtile ||
// stage one half-tile (2 x global_load_lds 16B) -> s_barrier -> lgkmcnt(0) ->
// setprio(1) 16xMFMA setprio(0) -> s_barrier}; counted vmcnt(4) ONLY at
// phases 4/8 so staging loads stay in flight across barriers (T4).
//
// Staging schedule (iter i computes t0=2i slot0 / t1=2i+1 slot1;
// each region is overwritten only after its last ds_read + a barrier):
//   ph1: s1-A.h0(t1)  ph2: s1-A.h1(t1)   [slot1-A free after prev ph7]
//   ph3: s0-B.h0(t0+2) ph4: s0-B.h1      [slot0-B fully read after ph2]
//   ph5: s0-A.h0(t0+2) ph6: s0-A.h1      [slot0-A fully read after ph3]
//   ph7: s1-B.h0(t1+2) ph8: s1-B.h1      [slot1-B fully read after ph6]
// vmcnt(4) at ph4 leaves {ph3,ph4} outstanding, forcing everything ph5-8
// reads landed; vmcnt(4) at ph8 leaves {ph7,ph8}, forcing next-ph1's data.
// Last iteration peeled: no next-tile stages, vmcnt(0) at ph4.
//
// LDS swizzle (rule #21, both-sides): rows are 128B -> full 3-bit XOR
// chunk ^= (row&7); applied as inverse-swizzled GLOBAL source for
// global_load_lds (dest stays linear) + swizzled ds_read address.
// ---------------------------------------------------------------------------
__global__ __launch_bounds__(512, 2) void gemm_exp_kernel(
    const __bf16* __restrict__ A, const __bf16* __restrict__ B,
    const float* __restrict__ sq, const float* __restrict__ ru,
    float* __restrict__ rowsum) {
    __shared__ __bf16 sA[2 * 256 * 64];   // 64 KiB
    __shared__ __bf16 sB[2 * 256 * 64];   // 64 KiB
    const int tid  = threadIdx.x;
    const int wave = tid >> 6, lane = tid & 63;
    const int wm = wave >> 2, wn = wave & 3;        // 2 x 4 wave grid
    const int q4 = lane >> 4, m16 = lane & 15, m8 = m16 & 7;
    const int rowBlock = blockIdx.x;   // 0..7   (fastest -> B-tile temporal locality)
    const int colBlock = blockIdx.y;   // 0..255

    // ---- staging addressing: wave covers 8 rows per issue; 64-row chunk/issue ----
    const int sr   = (wave << 3) + (lane >> 3);          // row within 64-row chunk
    const int csrc = (((lane & 7) ^ (lane >> 3)) << 3);  // inverse-swizzled src chunk
    const __bf16* gA = A + (((size_t)(rowBlock * 256 + sr)) << 9) + csrc;
    const __bf16* gB = B + (((size_t)(colBlock * 256 + sr)) << 9) + csrc;
    __bf16* lA = sA + (wave << 9);                        // wave-uniform LDS base
    __bf16* lB = sB + (wave << 9);

#define STG(g_, l_, s_, h_, q_, t_)                                           \
    gload_lds16((g_) + ((((h_) * 128 + (q_) * 64) << 9) + ((t_) << 6)),       \
                (l_) + (((s_) << 14) + (((h_) * 128 + (q_) * 64) << 6)))
#define STG_HA(s_, h_, t_) do { STG(gA, lA, s_, h_, 0, t_); STG(gA, lA, s_, h_, 1, t_); } while (0)
#define STG_HB(s_, h_, t_) do { STG(gB, lB, s_, h_, 0, t_); STG(gB, lB, s_, h_, 1, t_); } while (0)

    // ---- read-side addressing (swizzled chunk = (kk*4+q4) ^ (row&7)) ----
    const int aBase = (wm * 128 + m16) << 6;
    const int bBase = (wn * 64 + m16) << 6;
    const int chk0 = ((q4 ^ m8) << 3);
    const int chk1 = (((4 + q4) ^ m8) << 3);

    f32x4 acc[8][4] = {};
    bf16x8 aF[8], bLo[4], bHi[4];

#define LDS_A(s_, iH_)                                                                    \
    { _Pragma("unroll") for (int i2 = 0; i2 < 4; ++i2) {                                  \
        aF[i2 * 2 + 0] = *reinterpret_cast<const bf16x8*>(                                \
            &sA[((s_) << 14) + aBase + ((iH_) * 4 + i2) * 1024 + chk0]);                  \
        aF[i2 * 2 + 1] = *reinterpret_cast<const bf16x8*>(                                \
            &sA[((s_) << 14) + aBase + ((iH_) * 4 + i2) * 1024 + chk1]); } }
#define LDS_B(s_, jH_, dst_)                                                              \
    { _Pragma("unroll") for (int j2 = 0; j2 < 2; ++j2) {                                  \
        dst_[j2 * 2 + 0] = *reinterpret_cast<const bf16x8*>(                              \
            &sB[((s_) << 14) + bBase + ((jH_) * 2 + j2) * 1024 + chk0]);                  \
        dst_[j2 * 2 + 1] = *reinterpret_cast<const bf16x8*>(                              \
            &sB[((s_) << 14) + bBase + ((jH_) * 2 + j2) * 1024 + chk1]); } }

#define MMA(iH_, jH_, bX_)                                                                \
    { __builtin_amdgcn_s_setprio(1);                                                      \
      _Pragma("unroll") for (int i2 = 0; i2 < 4; ++i2)                                    \
      _Pragma("unroll") for (int j2 = 0; j2 < 2; ++j2)                                    \
      _Pragma("unroll") for (int kk = 0; kk < 2; ++kk)                                    \
          acc[(iH_) * 4 + i2][(jH_) * 2 + j2] = __builtin_amdgcn_mfma_f32_16x16x32_bf16(  \
              aF[i2 * 2 + kk], bX_[j2 * 2 + kk], acc[(iH_) * 4 + i2][(jH_) * 2 + j2],     \
              0, 0, 0);                                                                   \
      __builtin_amdgcn_s_setprio(0); }

#define BAR   __builtin_amdgcn_s_barrier()
#define LGKM0 do { asm volatile("s_waitcnt lgkmcnt(0)" ::: "memory");                     \
                   __builtin_amdgcn_sched_barrier(0); } while (0)
#define VM(n_) asm volatile("s_waitcnt vmcnt(" #n_ ")" ::: "memory")

    // prologue: K-tile 0 fully (slot0), K-tile 1 B-halves (slot1); leave t1-B in flight
    STG_HA(0, 0, 0); STG_HA(0, 1, 0); STG_HB(0, 0, 0); STG_HB(0, 1, 0);
    STG_HB(1, 0, 1); STG_HB(1, 1, 1);
    VM(4); BAR;

    // quadrant order per K-tile: Q1 i0-3 x j0-1, Q2 i0-3 x j2-3, Q3 i4-7 x j0-1, Q4 i4-7 x j2-3
#define ITERATION(t1_, tn0_, tn1_, FULL_, PH4W_, PH8W_)                                   \
    { /* ph1 */ LDS_A(0, 0); LDS_B(0, 0, bLo); STG_HA(1, 0, t1_);                         \
      BAR; LGKM0; MMA(0, 0, bLo); BAR;                                                    \
      /* ph2 */ LDS_B(0, 1, bHi); STG_HA(1, 1, t1_);                                      \
      BAR; LGKM0; MMA(0, 1, bHi); BAR;                                                    \
      /* ph3 */ LDS_A(0, 1); if (FULL_) STG_HB(0, 0, tn0_);                               \
      BAR; LGKM0; MMA(1, 0, bLo); BAR;                                                    \
      /* ph4 */ if (FULL_) STG_HB(0, 1, tn0_);                                            \
      BAR; LGKM0; MMA(1, 1, bHi); PH4W_; BAR;                                             \
      /* ph5 */ LDS_A(1, 0); LDS_B(1, 0, bLo); if (FULL_) STG_HA(0, 0, tn0_);             \
      BAR; LGKM0; MMA(0, 0, bLo); BAR;                                                    \
      /* ph6 */ LDS_B(1, 1, bHi); if (FULL_) STG_HA(0, 1, tn0_);                          \
      BAR; LGKM0; MMA(0, 1, bHi); BAR;                                                    \
      /* ph7 */ LDS_A(1, 1); if (FULL_) STG_HB(1, 0, tn1_);                               \
      BAR; LGKM0; MMA(1, 0, bLo); BAR;                                                    \
      /* ph8 */ if (FULL_) STG_HB(1, 1, tn1_);                                            \
      BAR; LGKM0; MMA(1, 1, bHi); PH8W_; BAR; }

    ITERATION(1, 2, 3, 1, VM(4), VM(4));
    ITERATION(3, 4, 5, 1, VM(4), VM(4));
    ITERATION(5, 6, 7, 1, VM(4), VM(4));
    ITERATION(7, 8, 9, 0, VM(0), ((void)0));   // peeled tail: drain before ph5

#undef ITERATION
#undef STG
#undef STG_HA
#undef STG_HB
#undef LDS_A
#undef LDS_B
#undef MMA
#undef BAR
#undef LGKM0
#undef VM

    // ---- epilogue: logits -> exp -> per-row sums (registers only, no barrier) ----
    float ruv[4];
#pragma unroll
    for (int j = 0; j < 4; ++j)
        ruv[j] = ru[colBlock * 256 + wn * 64 + j * 16 + m16];
    const int growBase = rowBlock * 256 + wm * 128 + q4 * 4;
#pragma unroll
    for (int i = 0; i < 8; ++i) {
#pragma unroll
        for (int r = 0; r < 4; ++r) {
            const int grow = growBase + i * 16 + r;
            const float sv = sq[grow];
            float s = 0.f;
#pragma unroll
            for (int j = 0; j < 4; ++j)
                s += __expf(acc[i][j][r] * sv * ruv[j]);
#pragma unroll
            for (int off = 1; off < 16; off <<= 1)
                s += __shfl_xor(s, off, 64);
            if (m16 == 0) atomicAdd(&rowsum[grow], s);
        }
    }
}

// ---------------------------------------------------------------------------
// Kernel 3: loss = mean(log(rowsum) - lpos)   (unchanged)
// ---------------------------------------------------------------------------
__global__ __launch_bounds__(256) void finalize_kernel(
    const float* __restrict__ rowsum, const float* __restrict__ lpos,
    float* __restrict__ out) {
    const int tid = threadIdx.x;
    float acc = 0.f;
    for (int n = tid; n < N_ROWS; n += 256)
        acc += __logf(rowsum[n]) - lpos[n];
#pragma unroll
    for (int off = 32; off > 0; off >>= 1) acc += __shfl_xor(acc, off, 64);
    __shared__ float red[4];
    if ((tid & 63) == 0) red[tid >> 6] = acc;
    __syncthreads();
    if (tid == 0) out[0] = (red[0] + red[1] + red[2] + red[3]) * (1.0f / (float)N_ROWS);
}

extern "C" void kernel_launch(void* const* d_in, const int* in_sizes, int n_in,
                              void* d_out, int out_size, void* d_ws, size_t ws_size,
                              hipStream_t stream) {
    const float* query = (const float*)d_in[0];
    const float* keys  = (const float*)d_in[1];
    const float* queue = (const float*)d_in[2];

    char* ws = (char*)d_ws;
    __bf16* Abf = (__bf16*)ws;  ws += (size_t)N_ROWS * D_DIM * sizeof(__bf16);   // 2 MB
    __bf16* Bbf = (__bf16*)ws;  ws += (size_t)K_NEG  * D_DIM * sizeof(__bf16);   // 64 MB
    float*  sq   = (float*)ws;  ws += (size_t)N_ROWS * sizeof(float);
    float*  ru   = (float*)ws;  ws += (size_t)K_NEG  * sizeof(float);
    float*  lpos = (float*)ws;  ws += (size_t)N_ROWS * sizeof(float);
    float*  rsum = (float*)ws;  ws += (size_t)N_ROWS * sizeof(float);

    prep_all_kernel<<<N_ROWS / 4 + K_NEG / 4, 256, 0, stream>>>(
        query, keys, queue, Abf, Bbf, sq, ru, lpos, rsum);
    gemm_exp_kernel<<<dim3(N_ROWS / 256, K_NEG / 256), 512, 0, stream>>>(
        Abf, Bbf, sq, ru, rsum);
    finalize_kernel<<<1, 256, 0, stream>>>(rsum, lpos, (float*)d_out);
}

// Round 2
// 389.287 us; speedup vs baseline: 1.2618x; 1.2618x over previous
//
#include <hip/hip_runtime.h>
#include <hip/hip_bf16.h>
#include <math.h>

// Problem constants (fixed by setup_inputs): N=2048, D=512, K=65536
#define N_ROWS 2048
#define D_DIM  512
#define K_NEG  65536
#define INV_T  5.0f   // 1/0.2
#define NC     4      // colBlocks processed per block (epilogue amortization)
#define NT     (NC * 16)   // flat pipeline iterations: NC colBlocks x 16 kt

typedef __bf16 bf16x8 __attribute__((ext_vector_type(8)));
typedef float  f32x4  __attribute__((ext_vector_type(4)));

__device__ __forceinline__ void gload_lds16(const __bf16* g, __bf16* l) {
    __builtin_amdgcn_global_load_lds(
        (const __attribute__((address_space(1))) void*)g,
        (__attribute__((address_space(3))) void*)l, 16, 0, 0);
}

// ---------------------------------------------------------------------------
// Kernel 1 (merged preps), grid-strided per G11 (round-2 change).
// Old version: 16896 tiny blocks (1 wave/row, 4 rows/block) -> launch-rate
// bound, ~4x its 33us BW roofline.  New: 2304 blocks.
//  blocks [0, 256):     q/k rows; 8 rows/block, 2 rows/wave.
//  blocks [256, 2304):  queue rows; 32 rows/block, 8 consecutive rows/wave
//                       (unrolled -> load ILP across rows).
// Per row (one wave): 2x float4 per lane = 2KB contiguous; 6-step shfl
// reduce; bf16x8 store (16B/lane).
// ---------------------------------------------------------------------------
__global__ __launch_bounds__(256) void prep_all_kernel(
    const float* __restrict__ query, const float* __restrict__ keys,
    const float* __restrict__ queue,
    __bf16* __restrict__ Abf, __bf16* __restrict__ Bbf,
    float* __restrict__ sq, float* __restrict__ ru,
    float* __restrict__ lpos, float* __restrict__ rowsum) {
    const int wave = threadIdx.x >> 6;
    const int lane = threadIdx.x & 63;
    if (blockIdx.x < 256) {
        // ---- query/keys: rows [blockIdx.x*8 + wave*2, +2) ----
#pragma unroll
        for (int rr = 0; rr < 2; ++rr) {
            const int row = (blockIdx.x << 3) + (wave << 1) + rr;
            const float4* qv = reinterpret_cast<const float4*>(query + (size_t)row * D_DIM) + lane * 2;
            const float4* kv = reinterpret_cast<const float4*>(keys  + (size_t)row * D_DIM) + lane * 2;
            float4 q0 = qv[0], q1 = qv[1];
            float4 k0 = kv[0], k1 = kv[1];
            float ssq = q0.x*q0.x + q0.y*q0.y + q0.z*q0.z + q0.w*q0.w
                      + q1.x*q1.x + q1.y*q1.y + q1.z*q1.z + q1.w*q1.w;
            float ssk = k0.x*k0.x + k0.y*k0.y + k0.z*k0.z + k0.w*k0.w
                      + k1.x*k1.x + k1.y*k1.y + k1.z*k1.z + k1.w*k1.w;
            float dot = q0.x*k0.x + q0.y*k0.y + q0.z*k0.z + q0.w*k0.w
                      + q1.x*k1.x + q1.y*k1.y + q1.z*k1.z + q1.w*k1.w;
#pragma unroll
            for (int off = 32; off > 0; off >>= 1) {
                ssq += __shfl_xor(ssq, off, 64);
                ssk += __shfl_xor(ssk, off, 64);
                dot += __shfl_xor(dot, off, 64);
            }
            bf16x8 o;
            o[0] = (__bf16)q0.x; o[1] = (__bf16)q0.y; o[2] = (__bf16)q0.z; o[3] = (__bf16)q0.w;
            o[4] = (__bf16)q1.x; o[5] = (__bf16)q1.y; o[6] = (__bf16)q1.z; o[7] = (__bf16)q1.w;
            reinterpret_cast<bf16x8*>(Abf + (size_t)row * D_DIM)[lane] = o;
            if (lane == 0) {
                float qn = sqrtf(ssq), kn = sqrtf(ssk);
                float lp = dot / fmaxf(qn * kn, 1e-8f) * INV_T;
                sq[row]     = INV_T / fmaxf(qn, 1e-8f);
                lpos[row]   = lp;
                rowsum[row] = __expf(lp);   // positive-logit term; also inits accumulator
            }
        }
    } else {
        // ---- queue: rows [(b-256)*32 + wave*8, +8) ----
        const int qb = blockIdx.x - 256;
#pragma unroll
        for (int rr = 0; rr < 8; ++rr) {
            const int row = (qb << 5) + (wave << 3) + rr;
            const float4* uv = reinterpret_cast<const float4*>(queue + (size_t)row * D_DIM) + lane * 2;
            float4 u0 = uv[0], u1 = uv[1];
            float ss = u0.x*u0.x + u0.y*u0.y + u0.z*u0.z + u0.w*u0.w
                     + u1.x*u1.x + u1.y*u1.y + u1.z*u1.z + u1.w*u1.w;
#pragma unroll
            for (int off = 32; off > 0; off >>= 1) ss += __shfl_xor(ss, off, 64);
            bf16x8 o;
            o[0] = (__bf16)u0.x; o[1] = (__bf16)u0.y; o[2] = (__bf16)u0.z; o[3] = (__bf16)u0.w;
            o[4] = (__bf16)u1.x; o[5] = (__bf16)u1.y; o[6] = (__bf16)u1.z; o[7] = (__bf16)u1.w;
            reinterpret_cast<bf16x8*>(Bbf + (size_t)row * D_DIM)[lane] = o;
            if (lane == 0) ru[row] = 1.0f / fmaxf(sqrtf(ss), 1e-8f);
        }
    }
}

// ---------------------------------------------------------------------------
// Kernel 2: NT-GEMM with fused exp-rowsum.  (REVERTED to round-0 proven
// version — 195us, 705 TF effective, the 2-phase structural ceiling.)
// 128x128 tile, BK=32, 4 waves (2x2), 4x4 frags of 16x16x32 bf16 MFMA.
// SINGLE-barrier double-buffered pipeline over a flat t-loop
// (NC colBlocks x 16 kt).  Per iter:
//   barrier  (drains loads(t), issued one full MFMA stage ago)
//   issue loads(t+1) -> buf^1     (overlaps with this iter's compute)
//   ds_read buf + 16 MFMA
// LDS source-address XOR swizzle kept (bank conflicts measured 0).
// Grid rowBlock-fastest (B-tile temporal locality; XCD decode regressed).
// NOTE round-1 post-mortem: 256x256 8-phase port regressed to 333us
// (MfmaUtil 16.5%) — K=512 gives only 4 iterations, pipeline never fills;
// matches m232's failed 8-phase ports.  Do not retry without derived waits.
// ---------------------------------------------------------------------------
__global__ __launch_bounds__(256, 3) void gemm_exp_kernel(
    const __bf16* __restrict__ A, const __bf16* __restrict__ B,
    const float* __restrict__ sq, const float* __restrict__ ru,
    float* __restrict__ rowsum) {
    __shared__ __bf16 sA[2 * 4096];
    __shared__ __bf16 sB[2 * 4096];
    const int tid  = threadIdx.x;
    const int wave = tid >> 6, lane = tid & 63;
    const int rowBlock = blockIdx.x;   // 0..15  (fastest -> B-tile temporal locality)
    const int colGroup = blockIdx.y;   // 0..127 (NC=4 colBlocks each)

    const int wm = wave >> 1, wn = wave & 1;
    const int q4 = lane >> 4, m16 = lane & 15;

    // staging lane map: lane = r4*4 + c2; LDS slot (r4,c2) <- global chunk
    // g = c2 ^ ((r4>>1)&3)  (source-address swizzle; dest is uniform+lane*16)
    const int r4 = lane >> 2, c2 = lane & 3;
    const int gsw = c2 ^ ((r4 >> 1) & 3);
    const int j0 = wave, j1 = wave + 4;          // 16-row chunks this wave stages
    const __bf16* gA  = A + (((size_t)(rowBlock * 128 + r4)) << 9) + (gsw << 3);
    const __bf16* gB0 = B + (((size_t)(colGroup * NC * 128 + r4)) << 9) + (gsw << 3);
    const int rsw = (q4 ^ ((m16 >> 1) & 3)) << 3;   // read-side swizzled chunk offset

    // hoisted row scales (same rows for every colBlock)
    float sqv[4][4];
#pragma unroll
    for (int i = 0; i < 4; ++i)
#pragma unroll
        for (int r = 0; r < 4; ++r)
            sqv[i][r] = sq[rowBlock * 128 + wm * 64 + i * 16 + q4 * 4 + r];

    float srow[4][4] = {{0.f,0.f,0.f,0.f},{0.f,0.f,0.f,0.f},
                        {0.f,0.f,0.f,0.f},{0.f,0.f,0.f,0.f}};
    f32x4 acc[4][4] = {};

    // stage(t, bufsel): issue 4 global_load_lds for iteration t
#define STAGE(T, BUF) do {                                                        \
        const int cb_ = (T) >> 4, kof_ = ((T) & 15) * 32;                         \
        const __bf16* gBc_ = gB0 + ((size_t)cb_ << 16);                           \
        __bf16* dA_ = &sA[(BUF) * 4096];                                          \
        __bf16* dB_ = &sB[(BUF) * 4096];                                          \
        gload_lds16(gA  + (size_t)j0 * 16 * D_DIM + kof_, &dA_[j0 * 512]);        \
        gload_lds16(gA  + (size_t)j1 * 16 * D_DIM + kof_, &dA_[j1 * 512]);        \
        gload_lds16(gBc_ + (size_t)j0 * 16 * D_DIM + kof_, &dB_[j0 * 512]);       \
        gload_lds16(gBc_ + (size_t)j1 * 16 * D_DIM + kof_, &dB_[j1 * 512]);       \
    } while (0)

    STAGE(0, 0);

    for (int t = 0; t < NT; ++t) {
        const int cur = t & 1;
        __syncthreads();                  // drains loads(t) (one stage in flight)
        if (t + 1 < NT) STAGE(t + 1, cur ^ 1);

        const __bf16* bA = &sA[cur * 4096];
        const __bf16* bB = &sB[cur * 4096];
        bf16x8 af[4], bq[4];
#pragma unroll
        for (int i = 0; i < 4; ++i)
            af[i] = *reinterpret_cast<const bf16x8*>(&bA[(wm * 64 + i * 16 + m16) * 32 + rsw]);
#pragma unroll
        for (int j = 0; j < 4; ++j)
            bq[j] = *reinterpret_cast<const bf16x8*>(&bB[(wn * 64 + j * 16 + m16) * 32 + rsw]);
#pragma unroll
        for (int i = 0; i < 4; ++i)
#pragma unroll
            for (int j = 0; j < 4; ++j)
                acc[i][j] = __builtin_amdgcn_mfma_f32_16x16x32_bf16(af[i], bq[j], acc[i][j], 0, 0, 0);

        if ((t & 15) == 15) {             // colBlock done: exp-accumulate, reset acc
            const int colBlock = colGroup * NC + (t >> 4);
            float ruv[4];
#pragma unroll
            for (int j = 0; j < 4; ++j)
                ruv[j] = ru[colBlock * 128 + wn * 64 + j * 16 + m16];
#pragma unroll
            for (int i = 0; i < 4; ++i)
#pragma unroll
                for (int r = 0; r < 4; ++r) {
                    float s = 0.f;
#pragma unroll
                    for (int j = 0; j < 4; ++j)
                        s += __expf(acc[i][j][r] * sqv[i][r] * ruv[j]);
                    srow[i][r] += s;
                    acc[i][0][r] = 0.f; acc[i][1][r] = 0.f;
                    acc[i][2][r] = 0.f; acc[i][3][r] = 0.f;
                }
        }
    }
#undef STAGE

    // one shuffle-reduce + atomic per row per block
#pragma unroll
    for (int i = 0; i < 4; ++i)
#pragma unroll
        for (int r = 0; r < 4; ++r) {
            float s = srow[i][r];
#pragma unroll
            for (int off = 1; off < 16; off <<= 1)
                s += __shfl_xor(s, off, 64);
            if (m16 == 0) {
                const int grow = rowBlock * 128 + wm * 64 + i * 16 + q4 * 4 + r;
                atomicAdd(&rowsum[grow], s);
            }
        }
}

// ---------------------------------------------------------------------------
// Kernel 3: loss = mean(log(rowsum) - lpos)
// ---------------------------------------------------------------------------
__global__ __launch_bounds__(256) void finalize_kernel(
    const float* __restrict__ rowsum, const float* __restrict__ lpos,
    float* __restrict__ out) {
    const int tid = threadIdx.x;
    float acc = 0.f;
    for (int n = tid; n < N_ROWS; n += 256)
        acc += __logf(rowsum[n]) - lpos[n];
#pragma unroll
    for (int off = 32; off > 0; off >>= 1) acc += __shfl_xor(acc, off, 64);
    __shared__ float red[4];
    if ((tid & 63) == 0) red[tid >> 6] = acc;
    __syncthreads();
    if (tid == 0) out[0] = (red[0] + red[1] + red[2] + red[3]) * (1.0f / (float)N_ROWS);
}

extern "C" void kernel_launch(void* const* d_in, const int* in_sizes, int n_in,
                              void* d_out, int out_size, void* d_ws, size_t ws_size,
                              hipStream_t stream) {
    const float* query = (const float*)d_in[0];
    const float* keys  = (const float*)d_in[1];
    const float* queue = (const float*)d_in[2];

    char* ws = (char*)d_ws;
    __bf16* Abf = (__bf16*)ws;  ws += (size_t)N_ROWS * D_DIM * sizeof(__bf16);   // 2 MB
    __bf16* Bbf = (__bf16*)ws;  ws += (size_t)K_NEG  * D_DIM * sizeof(__bf16);   // 64 MB
    float*  sq   = (float*)ws;  ws += (size_t)N_ROWS * sizeof(float);
    float*  ru   = (float*)ws;  ws += (size_t)K_NEG  * sizeof(float);
    float*  lpos = (float*)ws;  ws += (size_t)N_ROWS * sizeof(float);
    float*  rsum = (float*)ws;  ws += (size_t)N_ROWS * sizeof(float);

    prep_all_kernel<<<2304, 256, 0, stream>>>(
        query, keys, queue, Abf, Bbf, sq, ru, lpos, rsum);
    gemm_exp_kernel<<<dim3(N_ROWS / 128, K_NEG / 128 / NC), 256, 0, stream>>>(
        Abf, Bbf, sq, ru, rsum);
    finalize_kernel<<<1, 256, 0, stream>>>(rsum, lpos, (float*)d_out);
}

// Round 3
// 310.794 us; speedup vs baseline: 1.5804x; 1.2526x over previous
//
#include <hip/hip_runtime.h>
#include <hip/hip_bf16.h>
#include <math.h>

// Problem constants (fixed by setup_inputs): N=2048, D=512, K=65536
#define N_ROWS 2048
#define D_DIM  512
#define K_NEG  65536
#define INV_T  5.0f   // 1/0.2
#define NC     4      // colBlocks processed per block (epilogue amortization)
#define NT     (NC * 8)    // flat pipeline iterations: NC colBlocks x 8 kt (K=64 each)

typedef int i32x4 __attribute__((ext_vector_type(4)));

__device__ __forceinline__ void gload_lds16(const char* g, char* l) {
    __builtin_amdgcn_global_load_lds(
        (const __attribute__((address_space(1))) void*)g,
        (__attribute__((address_space(3))) void*)l, 16, 0, 0);
}

// i8 MFMA via inline asm (ISA §10: A=4 VGPR, B=4 VGPR, C/D=4; VGPR-form legal
// on gfx950 unified file).  "+v" ties C and D -> in-place accumulate.
// Hazard note: every acc's last MFMA is >=15 MFMA-issues (~75cy) before the
// epilogue's first VALU read of it -> no s_nop needed.
__device__ __forceinline__ void mfma_i8(i32x4& c, i32x4 a, i32x4 b) {
    asm volatile("v_mfma_i32_16x16x64_i8 %0, %1, %2, %0"
                 : "+v"(c) : "v"(a), "v"(b));
}

// quantize 4 floats by qm, round-nearest, pack to one i32 (byte0=x0..byte3=x3)
__device__ __forceinline__ int pack4(float x0, float x1, float x2, float x3, float qm) {
    const int a = (int)rintf(x0 * qm), b = (int)rintf(x1 * qm);
    const int c = (int)rintf(x2 * qm), d = (int)rintf(x3 * qm);
    return (a & 255) | ((b & 255) << 8) | ((c & 255) << 16) | (d << 24);
}

// ---------------------------------------------------------------------------
// Kernel 1 (merged preps): round-3 change — emit per-row symmetric i8 + scales.
//  blocks [0, 256):     q/k rows; 2 rows/wave.  fp32-exact lpos/qn/kn; quantize
//                       q -> Ai8 with step mxq/127; fA = step*INV_T/qn.
//  blocks [256, 2304):  queue rows; 8 rows/wave. Bi8 + fB = step/un.
// Quant error ~0.9% on the dot -> ~2e-3 absolute on logits -> ~1e-5 on loss.
// ---------------------------------------------------------------------------
__global__ __launch_bounds__(256) void prep_all_kernel(
    const float* __restrict__ query, const float* __restrict__ keys,
    const float* __restrict__ queue,
    char* __restrict__ Ai8, char* __restrict__ Bi8,
    float* __restrict__ fA, float* __restrict__ fB,
    float* __restrict__ lpos, float* __restrict__ rowsum) {
    const int wave = threadIdx.x >> 6;
    const int lane = threadIdx.x & 63;
    if (blockIdx.x < 256) {
#pragma unroll
        for (int rr = 0; rr < 2; ++rr) {
            const int row = (blockIdx.x << 3) + (wave << 1) + rr;
            const float4* qv = reinterpret_cast<const float4*>(query + (size_t)row * D_DIM) + lane * 2;
            const float4* kv = reinterpret_cast<const float4*>(keys  + (size_t)row * D_DIM) + lane * 2;
            float4 q0 = qv[0], q1 = qv[1];
            float4 k0 = kv[0], k1 = kv[1];
            float ssq = q0.x*q0.x + q0.y*q0.y + q0.z*q0.z + q0.w*q0.w
                      + q1.x*q1.x + q1.y*q1.y + q1.z*q1.z + q1.w*q1.w;
            float ssk = k0.x*k0.x + k0.y*k0.y + k0.z*k0.z + k0.w*k0.w
                      + k1.x*k1.x + k1.y*k1.y + k1.z*k1.z + k1.w*k1.w;
            float dot = q0.x*k0.x + q0.y*k0.y + q0.z*k0.z + q0.w*k0.w
                      + q1.x*k1.x + q1.y*k1.y + q1.z*k1.z + q1.w*k1.w;
            float amx = fmaxf(fmaxf(fmaxf(fabsf(q0.x), fabsf(q0.y)),
                                    fmaxf(fabsf(q0.z), fabsf(q0.w))),
                              fmaxf(fmaxf(fabsf(q1.x), fabsf(q1.y)),
                                    fmaxf(fabsf(q1.z), fabsf(q1.w))));
#pragma unroll
            for (int off = 32; off > 0; off >>= 1) {
                ssq += __shfl_xor(ssq, off, 64);
                ssk += __shfl_xor(ssk, off, 64);
                dot += __shfl_xor(dot, off, 64);
                amx = fmaxf(amx, __shfl_xor(amx, off, 64));
            }
            const float qm = 127.0f / amx;
            const int p0 = pack4(q0.x, q0.y, q0.z, q0.w, qm);
            const int p1 = pack4(q1.x, q1.y, q1.z, q1.w, qm);
            reinterpret_cast<int2*>(Ai8 + (size_t)row * D_DIM)[lane] = make_int2(p0, p1);
            if (lane == 0) {
                float qn = sqrtf(ssq), kn = sqrtf(ssk);
                float lp = dot / fmaxf(qn * kn, 1e-8f) * INV_T;
                fA[row]     = amx * (INV_T / 127.0f) / fmaxf(qn, 1e-8f);
                lpos[row]   = lp;
                rowsum[row] = __expf(lp);   // positive-logit term; inits accumulator
            }
        }
    } else {
        const int qb = blockIdx.x - 256;
#pragma unroll
        for (int rr = 0; rr < 8; ++rr) {
            const int row = (qb << 5) + (wave << 3) + rr;
            const float4* uv = reinterpret_cast<const float4*>(queue + (size_t)row * D_DIM) + lane * 2;
            float4 u0 = uv[0], u1 = uv[1];
            float ss = u0.x*u0.x + u0.y*u0.y + u0.z*u0.z + u0.w*u0.w
                     + u1.x*u1.x + u1.y*u1.y + u1.z*u1.z + u1.w*u1.w;
            float amx = fmaxf(fmaxf(fmaxf(fabsf(u0.x), fabsf(u0.y)),
                                    fmaxf(fabsf(u0.z), fabsf(u0.w))),
                              fmaxf(fmaxf(fabsf(u1.x), fabsf(u1.y)),
                                    fmaxf(fabsf(u1.z), fabsf(u1.w))));
#pragma unroll
            for (int off = 32; off > 0; off >>= 1) {
                ss  += __shfl_xor(ss, off, 64);
                amx = fmaxf(amx, __shfl_xor(amx, off, 64));
            }
            const float qm = 127.0f / amx;
            const int p0 = pack4(u0.x, u0.y, u0.z, u0.w, qm);
            const int p1 = pack4(u1.x, u1.y, u1.z, u1.w, qm);
            reinterpret_cast<int2*>(Bi8 + (size_t)row * D_DIM)[lane] = make_int2(p0, p1);
            if (lane == 0)
                fB[row] = amx * (1.0f / 127.0f) / fmaxf(sqrtf(ss), 1e-8f);
        }
    }
}

// ---------------------------------------------------------------------------
// Kernel 2: NT-GEMM (i8, K=64/instr) with fused exp-rowsum.
// Round-3 change: bf16 16x16x32 -> i8 v_mfma_i32_16x16x64 (2x rate, 2x K).
// An i8 128x64-K tile is 64 B/row x 128 rows — BYTE-IDENTICAL to the proven
// bf16 128x32-K tile, so staging / XOR swizzle / LDS layout are unchanged;
// only global strides (512 B rows), the MFMA, and the epilogue change.
// Per colBlock: 128 MFMA (was 256), 64 ds_read (was 128), staged bytes halved,
// NT 64 -> 32 (stall windows halve too).
// Correctness note: any consistent lane<->k byte convention applied to BOTH
// A and B operands yields the correct dot (k-permutation cancels), same
// argument that validates the double-XOR swizzle.
// Epilogue: logit = cvt(acc) * fA[row] * fB[col]; exp; srow accumulate.
// ---------------------------------------------------------------------------
__global__ __launch_bounds__(256, 3) void gemm_exp_kernel(
    const char* __restrict__ A, const char* __restrict__ B,
    const float* __restrict__ fA, const float* __restrict__ fB,
    float* __restrict__ rowsum) {
    __shared__ char sA[2 * 8192];
    __shared__ char sB[2 * 8192];
    const int tid  = threadIdx.x;
    const int wave = tid >> 6, lane = tid & 63;
    const int rowBlock = blockIdx.x;   // 0..15  (fastest -> B-tile temporal locality)
    const int colGroup = blockIdx.y;   // 0..127 (NC=4 colBlocks each)

    const int wm = wave >> 1, wn = wave & 1;
    const int q4 = lane >> 4, m16 = lane & 15;

    // staging lane map: lane = r4*4 + c2; LDS slot (r4,c2) <- global chunk
    // g = c2 ^ ((r4>>1)&3)  (source-address swizzle; dest is uniform+lane*16)
    const int r4 = lane >> 2, c2 = lane & 3;
    const int gsw = c2 ^ ((r4 >> 1) & 3);
    const int j0 = wave, j1 = wave + 4;          // 16-row chunks this wave stages
    const char* gA  = A + ((size_t)(rowBlock * 128 + r4)) * 512 + gsw * 16;
    const char* gB0 = B + ((size_t)(colGroup * NC * 128 + r4)) * 512 + gsw * 16;
    const int rsw = (q4 ^ ((m16 >> 1) & 3)) * 16;   // read-side swizzled byte offset

    // hoisted row dequant factors (same rows for every colBlock)
    float fAv[4][4];
#pragma unroll
    for (int i = 0; i < 4; ++i)
#pragma unroll
        for (int r = 0; r < 4; ++r)
            fAv[i][r] = fA[rowBlock * 128 + wm * 64 + i * 16 + q4 * 4 + r];

    float srow[4][4] = {{0.f,0.f,0.f,0.f},{0.f,0.f,0.f,0.f},
                        {0.f,0.f,0.f,0.f},{0.f,0.f,0.f,0.f}};
    i32x4 acc[4][4] = {};

    // stage(t, bufsel): issue 4 global_load_lds for iteration t
#define STAGE(T, BUF) do {                                                        \
        const int cb_ = (T) >> 3, kof_ = ((T) & 7) * 64;                          \
        const char* gBc_ = gB0 + ((size_t)cb_ << 16);                             \
        char* dA_ = &sA[(BUF) * 8192];                                            \
        char* dB_ = &sB[(BUF) * 8192];                                            \
        gload_lds16(gA   + (size_t)j0 * 16 * 512 + kof_, &dA_[j0 * 1024]);        \
        gload_lds16(gA   + (size_t)j1 * 16 * 512 + kof_, &dA_[j1 * 1024]);        \
        gload_lds16(gBc_ + (size_t)j0 * 16 * 512 + kof_, &dB_[j0 * 1024]);        \
        gload_lds16(gBc_ + (size_t)j1 * 16 * 512 + kof_, &dB_[j1 * 1024]);        \
    } while (0)

    STAGE(0, 0);

    for (int t = 0; t < NT; ++t) {
        const int cur = t & 1;
        __syncthreads();                  // drains loads(t) (one stage in flight)
        if (t + 1 < NT) STAGE(t + 1, cur ^ 1);

        const char* bA = &sA[cur * 8192];
        const char* bB = &sB[cur * 8192];
        i32x4 af[4], bq[4];
#pragma unroll
        for (int i = 0; i < 4; ++i)
            af[i] = *reinterpret_cast<const i32x4*>(&bA[(wm * 64 + i * 16 + m16) * 64 + rsw]);
#pragma unroll
        for (int j = 0; j < 4; ++j)
            bq[j] = *reinterpret_cast<const i32x4*>(&bB[(wn * 64 + j * 16 + m16) * 64 + rsw]);
#pragma unroll
        for (int i = 0; i < 4; ++i)
#pragma unroll
            for (int j = 0; j < 4; ++j)
                mfma_i8(acc[i][j], af[i], bq[j]);

        if ((t & 7) == 7) {               // colBlock done: exp-accumulate, reset acc
            const int colBlock = colGroup * NC + (t >> 3);
            float fBv[4];
#pragma unroll
            for (int j = 0; j < 4; ++j)
                fBv[j] = fB[colBlock * 128 + wn * 64 + j * 16 + m16];
#pragma unroll
            for (int i = 0; i < 4; ++i)
#pragma unroll
                for (int r = 0; r < 4; ++r) {
                    float s = 0.f;
#pragma unroll
                    for (int j = 0; j < 4; ++j)
                        s += __expf((float)acc[i][j][r] * fAv[i][r] * fBv[j]);
                    srow[i][r] += s;
                    acc[i][0][r] = 0; acc[i][1][r] = 0;
                    acc[i][2][r] = 0; acc[i][3][r] = 0;
                }
        }
    }
#undef STAGE

    // one shuffle-reduce + atomic per row per block
#pragma unroll
    for (int i = 0; i < 4; ++i)
#pragma unroll
        for (int r = 0; r < 4; ++r) {
            float s = srow[i][r];
#pragma unroll
            for (int off = 1; off < 16; off <<= 1)
                s += __shfl_xor(s, off, 64);
            if (m16 == 0) {
                const int grow = rowBlock * 128 + wm * 64 + i * 16 + q4 * 4 + r;
                atomicAdd(&rowsum[grow], s);
            }
        }
}

// ---------------------------------------------------------------------------
// Kernel 3: loss = mean(log(rowsum) - lpos)
// ---------------------------------------------------------------------------
__global__ __launch_bounds__(256) void finalize_kernel(
    const float* __restrict__ rowsum, const float* __restrict__ lpos,
    float* __restrict__ out) {
    const int tid = threadIdx.x;
    float acc = 0.f;
    for (int n = tid; n < N_ROWS; n += 256)
        acc += __logf(rowsum[n]) - lpos[n];
#pragma unroll
    for (int off = 32; off > 0; off >>= 1) acc += __shfl_xor(acc, off, 64);
    __shared__ float red[4];
    if ((tid & 63) == 0) red[tid >> 6] = acc;
    __syncthreads();
    if (tid == 0) out[0] = (red[0] + red[1] + red[2] + red[3]) * (1.0f / (float)N_ROWS);
}

extern "C" void kernel_launch(void* const* d_in, const int* in_sizes, int n_in,
                              void* d_out, int out_size, void* d_ws, size_t ws_size,
                              hipStream_t stream) {
    const float* query = (const float*)d_in[0];
    const float* keys  = (const float*)d_in[1];
    const float* queue = (const float*)d_in[2];

    char* ws = (char*)d_ws;
    char*  Ai8 = ws;            ws += (size_t)N_ROWS * D_DIM;                 // 1 MB
    char*  Bi8 = ws;            ws += (size_t)K_NEG  * D_DIM;                 // 32 MB
    float* fA   = (float*)ws;   ws += (size_t)N_ROWS * sizeof(float);
    float* fB   = (float*)ws;   ws += (size_t)K_NEG  * sizeof(float);
    float* lpos = (float*)ws;   ws += (size_t)N_ROWS * sizeof(float);
    float* rsum = (float*)ws;   ws += (size_t)N_ROWS * sizeof(float);

    prep_all_kernel<<<2304, 256, 0, stream>>>(
        query, keys, queue, Ai8, Bi8, fA, fB, lpos, rsum);
    gemm_exp_kernel<<<dim3(N_ROWS / 128, K_NEG / 128 / NC), 256, 0, stream>>>(
        Ai8, Bi8, fA, fB, rsum);
    finalize_kernel<<<1, 256, 0, stream>>>(rsum, lpos, (float*)d_out);
}